// Round 3
// baseline (112.570 us; speedup 1.0000x reference)
//
#include <hip/hip_runtime.h>
#include <hip/hip_bf16.h>

#define G_ 64
#define N_ 1024
#define DIN 128
#define DH 256
#define DOUT 10

typedef float floatx4 __attribute__((ext_vector_type(4)));
typedef short shortx8 __attribute__((ext_vector_type(8)));

__device__ __forceinline__ ushort f2bf(float f) {
  unsigned u = __builtin_bit_cast(unsigned, f);
  unsigned r = (u + 0x7FFFu + ((u >> 16) & 1u)) >> 16;   // RNE
  return (ushort)r;
}
__device__ __forceinline__ float bflo(unsigned q) {
  return __builtin_bit_cast(float, q << 16);
}
__device__ __forceinline__ float bfhi(unsigned q) {
  return __builtin_bit_cast(float, q & 0xFFFF0000u);
}

// ---------------------------------------------------------------------------
// k1 (fused): blocks 0..1023 — 64 nodes each: norminv + xb (bf16) + per-block
//   u partial (no atomics). float4 reads (2 nodes/wave/iter, 32-lane reduce),
//   uint2 packed bf16 writes -> full store rate.
// blocks 1024..1087 — W1 [128][256] fp32 -> w1t [256][128] bf16 (B^T).
// ---------------------------------------------------------------------------
__global__ __launch_bounds__(256) void k1_fused(
    const float* __restrict__ x, const float* __restrict__ W1,
    float* __restrict__ norminv, float* __restrict__ u_part,
    ushort* __restrict__ xb, ushort* __restrict__ w1t) {
  if (blockIdx.x >= 1024) {            // W1 transpose+convert tail (64 KB)
    const int wb = blockIdx.x - 1024;
    #pragma unroll
    for (int i = 0; i < 2; ++i) {
      const int idx = wb * 512 + i * 256 + threadIdx.x;   // 0..32767
      const int k = idx >> 8, d = idx & 255;
      w1t[d * DIN + k] = f2bf(W1[k * DH + d]);
    }
    return;
  }
  const int tid = threadIdx.x;
  const int wave = tid >> 6;
  const int lane = tid & 63;
  const int half = lane >> 5;          // which node of the pair
  const int l32 = lane & 31;           // d-quad index (d = l32*4..+3)
  __shared__ float red[8][DIN];        // 8 half-waves x 128 d
  float a0 = 0.f, a1 = 0.f, a2 = 0.f, a3 = 0.f;
  const int mbase = blockIdx.x * 64 + wave * 16;
  #pragma unroll
  for (int i = 0; i < 8; ++i) {
    const int m = mbase + i * 2 + half;
    const float4 v = ((const float4*)(x + (size_t)m * DIN))[l32];
    float ss = v.x * v.x + v.y * v.y + v.z * v.z + v.w * v.w;
    #pragma unroll
    for (int off = 16; off; off >>= 1) ss += __shfl_xor(ss, off, 64);
    const float ninv = rsqrtf(ss + 1e-24f);
    if (l32 == 0) norminv[m] = ninv;
    uint2 pk;
    pk.x = (unsigned)f2bf(v.x) | ((unsigned)f2bf(v.y) << 16);
    pk.y = (unsigned)f2bf(v.z) | ((unsigned)f2bf(v.w) << 16);
    ((uint2*)(xb + (size_t)m * DIN))[l32] = pk;
    a0 = fmaf(v.x, ninv, a0);
    a1 = fmaf(v.y, ninv, a1);
    a2 = fmaf(v.z, ninv, a2);
    a3 = fmaf(v.w, ninv, a3);
  }
  *(float4*)&red[tid >> 5][l32 * 4] = make_float4(a0, a1, a2, a3);
  __syncthreads();
  if (tid < DIN) {
    float t = 0.f;
    #pragma unroll
    for (int r = 0; r < 8; ++r) t += red[r][tid];
    u_part[blockIdx.x * DIN + tid] = t;   // race-free per-block partial
  }
}

// ---------------------------------------------------------------------------
// k2: hw_part[tile][d] = sum_{m in tile} s[m] * relu(x[m]@W1+b1)[d], bf16 MFMA.
// Grid = 64 g * 16 tiles (64 nodes); block = 4 waves, wave owns 64 d.
// u re-summed from 16 per-block partials (cheap); s in-block; no atomics.
// ---------------------------------------------------------------------------
__global__ __launch_bounds__(256) void k2_mfma(
    const ushort* __restrict__ xb, const ushort* __restrict__ w1t,
    const float* __restrict__ b1, const float* __restrict__ norminv,
    const float* __restrict__ u_part, float* __restrict__ hw_part) {
  const int g = blockIdx.x >> 4;
  const int mb = (blockIdx.x & 15) << 6;   // first node (in-graph) of tile
  const int tid = threadIdx.x;
  const int lane = tid & 63;
  const int wave = tid >> 6;
  const int quad = lane >> 4;
  const int l16 = lane & 15;
  __shared__ float u_lds[DIN];
  __shared__ float s_lds[64];

  if (tid < DIN) {                      // u = sum of 16 block partials
    float t = 0.f;
    const float* up = u_part + (size_t)(g << 4) * DIN + tid;
    #pragma unroll
    for (int r = 0; r < 16; ++r) t += up[r * DIN];
    u_lds[tid] = t;
  }
  __syncthreads();

  // s[m] = ninv[m]*(u . x[m]) - 1 ; 4 threads per node (32 elems each)
  {
    const int nd = tid >> 2;
    const int qq = tid & 3;
    const size_t m = (size_t)(g << 10) + mb + nd;
    const uint4* xr = (const uint4*)(xb + m * DIN + qq * 32);
    float p = 0.f;
    #pragma unroll
    for (int j = 0; j < 4; ++j) {
      const uint4 q = xr[j];
      const float* ub = &u_lds[qq * 32 + j * 8];
      p = fmaf(bflo(q.x), ub[0], p); p = fmaf(bfhi(q.x), ub[1], p);
      p = fmaf(bflo(q.y), ub[2], p); p = fmaf(bfhi(q.y), ub[3], p);
      p = fmaf(bflo(q.z), ub[4], p); p = fmaf(bfhi(q.z), ub[5], p);
      p = fmaf(bflo(q.w), ub[6], p); p = fmaf(bfhi(q.w), ub[7], p);
    }
    p += __shfl_xor(p, 1, 64);
    p += __shfl_xor(p, 2, 64);
    if (qq == 0) s_lds[nd] = p * norminv[m] - 1.0f;
  }
  __syncthreads();

  // B-frags: wave's 64-d slice of W1t (hoisted). B[k][n]: n=l16, k=quad*8+j.
  shortx8 bfr[4][4];   // [dt][kt]
  float b1v[4];
  #pragma unroll
  for (int dt = 0; dt < 4; ++dt) {
    const int d = (wave << 6) + (dt << 4) + l16;
    b1v[dt] = b1[d];
    #pragma unroll
    for (int kt = 0; kt < 4; ++kt)
      bfr[dt][kt] = *(const shortx8*)(w1t + (size_t)d * DIN + (kt << 5) + (quad << 3));
  }

  float wsum[4] = {0.f, 0.f, 0.f, 0.f};
  #pragma unroll
  for (int mt = 0; mt < 4; ++mt) {
    // A-frags: A[m][k]: m=l16, k=quad*8+j (16B contiguous per lane)
    const ushort* ar = xb + ((size_t)(g << 10) + mb + (mt << 4) + l16) * DIN;
    shortx8 af[4];
    #pragma unroll
    for (int kt = 0; kt < 4; ++kt)
      af[kt] = *(const shortx8*)(ar + (kt << 5) + (quad << 3));

    floatx4 acc[4] = {{0.f, 0.f, 0.f, 0.f}, {0.f, 0.f, 0.f, 0.f},
                      {0.f, 0.f, 0.f, 0.f}, {0.f, 0.f, 0.f, 0.f}};
    #pragma unroll
    for (int kt = 0; kt < 4; ++kt)
      #pragma unroll
      for (int dt = 0; dt < 4; ++dt)
        acc[dt] = __builtin_amdgcn_mfma_f32_16x16x32_bf16(af[kt], bfr[dt][kt],
                                                          acc[dt], 0, 0, 0);
    // bias + relu + s-weight; C layout: row(m) = quad*4+r, col(d) = l16
    #pragma unroll
    for (int dt = 0; dt < 4; ++dt) {
      float bs = 0.f;
      #pragma unroll
      for (int r = 0; r < 4; ++r) {
        const float h = fmaxf(acc[dt][r] + b1v[dt], 0.f);
        bs = fmaf(s_lds[(mt << 4) + (quad << 2) + r], h, bs);
      }
      wsum[dt] += bs;
    }
  }
  #pragma unroll
  for (int dt = 0; dt < 4; ++dt) {
    float w = wsum[dt];
    w += __shfl_xor(w, 16, 64);
    w += __shfl_xor(w, 32, 64);
    if (quad == 0)
      hw_part[(size_t)blockIdx.x * DH + (wave << 6) + (dt << 4) + l16] = w;
  }
}

// ---------------------------------------------------------------------------
// k3: sum 16 hw partials, pooled = hw/N @ W2 + b2, log_softmax.
// ---------------------------------------------------------------------------
__global__ __launch_bounds__(64) void k3_head(
    const float* __restrict__ hw_part, const float* __restrict__ W2,
    const float* __restrict__ b2, float* __restrict__ out) {
  const int g = blockIdx.x;
  const int t = threadIdx.x;
  __shared__ float hsum[DH];
  __shared__ float partial[40];
  __shared__ float p[DOUT];
  {
    float4 hs = make_float4(0.f, 0.f, 0.f, 0.f);
    #pragma unroll
    for (int r = 0; r < 16; ++r) {
      const float4 v = ((const float4*)(hw_part + (size_t)((g << 4) + r) * DH))[t];
      hs.x += v.x; hs.y += v.y; hs.z += v.z; hs.w += v.w;
    }
    ((float4*)hsum)[t] = hs;
  }
  __syncthreads();
  if (t < 40) {
    const int c = t % 10, q = t / 10;
    const float* hg = hsum + q * 64;
    float a = 0.f;
    #pragma unroll
    for (int k = 0; k < 64; ++k) a = fmaf(hg[k], W2[(q * 64 + k) * DOUT + c], a);
    partial[t] = a;
  }
  __syncthreads();
  if (t < DOUT) {
    p[t] = (partial[t] + partial[t + 10] + partial[t + 20] + partial[t + 30]) *
               (1.0f / N_) + b2[t];
  }
  __syncthreads();
  if (t < DOUT) {
    float mx = p[0];
    #pragma unroll
    for (int c = 1; c < DOUT; ++c) mx = fmaxf(mx, p[c]);
    float se = 0.f;
    #pragma unroll
    for (int c = 0; c < DOUT; ++c) se += expf(p[c] - mx);
    out[g * DOUT + t] = p[t] - (mx + logf(se));
  }
}

extern "C" void kernel_launch(void* const* d_in, const int* in_sizes, int n_in,
                              void* d_out, int out_size, void* d_ws, size_t ws_size,
                              hipStream_t stream) {
  const float* x  = (const float*)d_in[0];
  // d_in[1] = batch (sorted, equal-sized) -> unused
  const float* W1 = (const float*)d_in[2];
  const float* b1 = (const float*)d_in[3];
  const float* W2 = (const float*)d_in[4];
  const float* b2 = (const float*)d_in[5];
  float* out = (float*)d_out;

  // ws (floats): u_part[1024*128] hw_part[1024*256] norminv[65536]; then bf16
  float* u_part  = (float*)d_ws;
  float* hw_part = u_part + 1024 * DIN;
  float* norminv = hw_part + 1024 * DH;
  ushort* xb  = (ushort*)(norminv + (size_t)G_ * N_);   // [65536][128] bf16
  ushort* w1t = xb + (size_t)G_ * N_ * DIN;             // [256][128] bf16

  // Every ws location is written before it is read -> no memset, no atomics.
  k1_fused<<<1024 + 64, 256, 0, stream>>>(x, W1, norminv, u_part, xb, w1t);
  k2_mfma<<<G_ * 16, 256, 0, stream>>>(xb, w1t, b1, norminv, u_part, hw_part);
  k3_head<<<G_, 64, 0, stream>>>(hw_part, W2, b2, out);
}

// Round 5
// 112.480 us; speedup vs baseline: 1.0008x; 1.0008x over previous
//
#include <hip/hip_runtime.h>
#include <hip/hip_bf16.h>

#define G_ 64
#define N_ 1024
#define DIN 128
#define DH 256
#define DOUT 10

typedef float floatx4 __attribute__((ext_vector_type(4)));
typedef short shortx8 __attribute__((ext_vector_type(8)));

__device__ __forceinline__ ushort f2bf(float f) {
  unsigned u = __builtin_bit_cast(unsigned, f);
  unsigned r = (u + 0x7FFFu + ((u >> 16) & 1u)) >> 16;   // RNE
  return (ushort)r;
}
__device__ __forceinline__ float bflo(unsigned q) {
  return __builtin_bit_cast(float, q << 16);
}
__device__ __forceinline__ float bfhi(unsigned q) {
  return __builtin_bit_cast(float, q & 0xFFFF0000u);
}

// ---------------------------------------------------------------------------
// k1 (fused): blocks 0..1023 — 64 nodes each: norminv + xb (bf16) + per-block
//   u partial (no atomics). blocks 1024..1087 — W1 -> w1t bf16 (B^T).
// ---------------------------------------------------------------------------
__global__ __launch_bounds__(256) void k1_fused(
    const float* __restrict__ x, const float* __restrict__ W1,
    float* __restrict__ norminv, float* __restrict__ u_part,
    ushort* __restrict__ xb, ushort* __restrict__ w1t) {
  if (blockIdx.x >= 1024) {            // W1 transpose+convert tail (64 KB)
    const int wb = blockIdx.x - 1024;
    #pragma unroll
    for (int i = 0; i < 2; ++i) {
      const int idx = wb * 512 + i * 256 + threadIdx.x;   // 0..32767
      const int k = idx >> 8, d = idx & 255;
      w1t[d * DIN + k] = f2bf(W1[k * DH + d]);
    }
    return;
  }
  const int tid = threadIdx.x;
  const int wave = tid >> 6;
  const int lane = tid & 63;
  const int half = lane >> 5;          // which node of the pair
  const int l32 = lane & 31;           // d-quad index (d = l32*4..+3)
  __shared__ float red[8][DIN];        // 8 half-waves x 128 d
  float a0 = 0.f, a1 = 0.f, a2 = 0.f, a3 = 0.f;
  const int mbase = blockIdx.x * 64 + wave * 16;
  #pragma unroll
  for (int i = 0; i < 8; ++i) {
    const int m = mbase + i * 2 + half;
    const float4 v = ((const float4*)(x + (size_t)m * DIN))[l32];
    float ss = v.x * v.x + v.y * v.y + v.z * v.z + v.w * v.w;
    #pragma unroll
    for (int off = 16; off; off >>= 1) ss += __shfl_xor(ss, off, 64);
    const float ninv = rsqrtf(ss + 1e-24f);
    if (l32 == 0) norminv[m] = ninv;
    uint2 pk;
    pk.x = (unsigned)f2bf(v.x) | ((unsigned)f2bf(v.y) << 16);
    pk.y = (unsigned)f2bf(v.z) | ((unsigned)f2bf(v.w) << 16);
    ((uint2*)(xb + (size_t)m * DIN))[l32] = pk;
    a0 = fmaf(v.x, ninv, a0);
    a1 = fmaf(v.y, ninv, a1);
    a2 = fmaf(v.z, ninv, a2);
    a3 = fmaf(v.w, ninv, a3);
  }
  *(float4*)&red[tid >> 5][l32 * 4] = make_float4(a0, a1, a2, a3);
  __syncthreads();
  if (tid < DIN) {
    float t = 0.f;
    #pragma unroll
    for (int r = 0; r < 8; ++r) t += red[r][tid];
    u_part[blockIdx.x * DIN + tid] = t;   // race-free per-block partial
  }
}

// ---------------------------------------------------------------------------
// k2: hw_part[tile][d] = sum_{m in tile} s[m] * relu(x[m]@W1+b1)[d], bf16 MFMA.
// Grid = 64 g * 16 tiles (64 nodes); block = 4 waves, wave owns 64 d.
// ---------------------------------------------------------------------------
__global__ __launch_bounds__(256) void k2_mfma(
    const ushort* __restrict__ xb, const ushort* __restrict__ w1t,
    const float* __restrict__ b1, const float* __restrict__ norminv,
    const float* __restrict__ u_part, float* __restrict__ hw_part) {
  const int g = blockIdx.x >> 4;
  const int mb = (blockIdx.x & 15) << 6;   // first node (in-graph) of tile
  const int tid = threadIdx.x;
  const int lane = tid & 63;
  const int wave = tid >> 6;
  const int quad = lane >> 4;
  const int l16 = lane & 15;
  __shared__ float u_lds[DIN];
  __shared__ float s_lds[64];

  if (tid < DIN) {                      // u = sum of 16 block partials
    float t = 0.f;
    const float* up = u_part + (size_t)(g << 4) * DIN + tid;
    #pragma unroll
    for (int r = 0; r < 16; ++r) t += up[r * DIN];
    u_lds[tid] = t;
  }
  __syncthreads();

  // s[m] = ninv[m]*(u . x[m]) - 1 ; 4 threads per node (32 elems each)
  {
    const int nd = tid >> 2;
    const int qq = tid & 3;
    const size_t m = (size_t)(g << 10) + mb + nd;
    const uint4* xr = (const uint4*)(xb + m * DIN + qq * 32);
    float p = 0.f;
    #pragma unroll
    for (int j = 0; j < 4; ++j) {
      const uint4 q = xr[j];
      const float* ub = &u_lds[qq * 32 + j * 8];
      p = fmaf(bflo(q.x), ub[0], p); p = fmaf(bfhi(q.x), ub[1], p);
      p = fmaf(bflo(q.y), ub[2], p); p = fmaf(bfhi(q.y), ub[3], p);
      p = fmaf(bflo(q.z), ub[4], p); p = fmaf(bfhi(q.z), ub[5], p);
      p = fmaf(bflo(q.w), ub[6], p); p = fmaf(bfhi(q.w), ub[7], p);
    }
    p += __shfl_xor(p, 1, 64);
    p += __shfl_xor(p, 2, 64);
    if (qq == 0) s_lds[nd] = p * norminv[m] - 1.0f;
  }
  __syncthreads();

  // B-frags: wave's 64-d slice of W1t (hoisted). B[k][n]: n=l16, k=quad*8+j.
  shortx8 bfr[4][4];   // [dt][kt]
  float b1v[4];
  #pragma unroll
  for (int dt = 0; dt < 4; ++dt) {
    const int d = (wave << 6) + (dt << 4) + l16;
    b1v[dt] = b1[d];
    #pragma unroll
    for (int kt = 0; kt < 4; ++kt)
      bfr[dt][kt] = *(const shortx8*)(w1t + (size_t)d * DIN + (kt << 5) + (quad << 3));
  }

  float wsum[4] = {0.f, 0.f, 0.f, 0.f};
  #pragma unroll
  for (int mt = 0; mt < 4; ++mt) {
    // A-frags: A[m][k]: m=l16, k=quad*8+j (16B contiguous per lane)
    const ushort* ar = xb + ((size_t)(g << 10) + mb + (mt << 4) + l16) * DIN;
    shortx8 af[4];
    #pragma unroll
    for (int kt = 0; kt < 4; ++kt)
      af[kt] = *(const shortx8*)(ar + (kt << 5) + (quad << 3));

    floatx4 acc[4] = {{0.f, 0.f, 0.f, 0.f}, {0.f, 0.f, 0.f, 0.f},
                      {0.f, 0.f, 0.f, 0.f}, {0.f, 0.f, 0.f, 0.f}};
    #pragma unroll
    for (int kt = 0; kt < 4; ++kt)
      #pragma unroll
      for (int dt = 0; dt < 4; ++dt)
        acc[dt] = __builtin_amdgcn_mfma_f32_16x16x32_bf16(af[kt], bfr[dt][kt],
                                                          acc[dt], 0, 0, 0);
    // bias + relu + s-weight; C layout: row(m) = quad*4+r, col(d) = l16
    #pragma unroll
    for (int dt = 0; dt < 4; ++dt) {
      float bs = 0.f;
      #pragma unroll
      for (int r = 0; r < 4; ++r) {
        const float h = fmaxf(acc[dt][r] + b1v[dt], 0.f);
        bs = fmaf(s_lds[(mt << 4) + (quad << 2) + r], h, bs);
      }
      wsum[dt] += bs;
    }
  }
  #pragma unroll
  for (int dt = 0; dt < 4; ++dt) {
    float w = wsum[dt];
    w += __shfl_xor(w, 16, 64);
    w += __shfl_xor(w, 32, 64);
    if (quad == 0)
      hw_part[(size_t)blockIdx.x * DH + (wave << 6) + (dt << 4) + l16] = w;
  }
}

// ---------------------------------------------------------------------------
// k3 (v2): 256 threads/block. W2 staged coalesced into LDS (10 KB); hsum and
// the 40 length-64 dot products run entirely from LDS -> no strided global
// reads, no per-thread 64x ~200cyc L2 latency chain.
// ---------------------------------------------------------------------------
__global__ __launch_bounds__(256) void k3_head(
    const float* __restrict__ hw_part, const float* __restrict__ W2,
    const float* __restrict__ b2, float* __restrict__ out) {
  const int g = blockIdx.x;
  const int t = threadIdx.x;
  __shared__ float w2l[DH * DOUT];   // 2560 floats
  __shared__ float hsum[DH];
  __shared__ float partial[40];
  __shared__ float p[DOUT];
  #pragma unroll
  for (int i = 0; i < (DH * DOUT) / 256; ++i)   // coalesced W2 stage
    w2l[i * 256 + t] = W2[i * 256 + t];
  {
    float hs = 0.f;
    const float* hp = hw_part + (size_t)(g << 4) * DH + t;
    #pragma unroll
    for (int r = 0; r < 16; ++r) hs += hp[r * DH];
    hsum[t] = hs;
  }
  __syncthreads();
  if (t < 40) {
    const int c = t % 10, q = t / 10;
    const float* hg = hsum + q * 64;
    const float* wg = w2l + (q * 64) * DOUT + c;
    float a = 0.f;
    #pragma unroll
    for (int k = 0; k < 64; ++k) a = fmaf(hg[k], wg[k * DOUT], a);
    partial[t] = a;
  }
  __syncthreads();
  if (t < DOUT) {
    p[t] = (partial[t] + partial[t + 10] + partial[t + 20] + partial[t + 30]) *
               (1.0f / N_) + b2[t];
  }
  __syncthreads();
  if (t < DOUT) {
    float mx = p[0];
    #pragma unroll
    for (int c = 1; c < DOUT; ++c) mx = fmaxf(mx, p[c]);
    float se = 0.f;
    #pragma unroll
    for (int c = 0; c < DOUT; ++c) se += expf(p[c] - mx);
    out[g * DOUT + t] = p[t] - (mx + logf(se));
  }
}

extern "C" void kernel_launch(void* const* d_in, const int* in_sizes, int n_in,
                              void* d_out, int out_size, void* d_ws, size_t ws_size,
                              hipStream_t stream) {
  const float* x  = (const float*)d_in[0];
  // d_in[1] = batch (sorted, equal-sized) -> unused
  const float* W1 = (const float*)d_in[2];
  const float* b1 = (const float*)d_in[3];
  const float* W2 = (const float*)d_in[4];
  const float* b2 = (const float*)d_in[5];
  float* out = (float*)d_out;

  // ws (floats): u_part[1024*128] hw_part[1024*256] norminv[65536]; then bf16
  float* u_part  = (float*)d_ws;
  float* hw_part = u_part + 1024 * DIN;
  float* norminv = hw_part + 1024 * DH;
  ushort* xb  = (ushort*)(norminv + (size_t)G_ * N_);   // [65536][128] bf16
  ushort* w1t = xb + (size_t)G_ * N_ * DIN;             // [256][128] bf16

  // Every ws location is written before it is read -> no memset, no atomics.
  k1_fused<<<1024 + 64, 256, 0, stream>>>(x, W1, norminv, u_part, xb, w1t);
  k2_mfma<<<G_ * 16, 256, 0, stream>>>(xb, w1t, b1, norminv, u_part, hw_part);
  k3_head<<<G_, 256, 0, stream>>>(hw_part, W2, b2, out);
}